// Round 16
// baseline (2082.839 us; speedup 1.0000x reference)
//
#include <hip/hip_runtime.h>

#define L_ 6
#define E_ 768
#define H_ 12
#define FF_ 3072

typedef __attribute__((ext_vector_type(8))) short bh8;     // 8 bf16 (4 VGPRs)
typedef __attribute__((ext_vector_type(4))) float f32x4;

__device__ inline ushort f2bf(float f) {
  unsigned u = __builtin_bit_cast(unsigned, f);
  u += 0x7fffu + ((u >> 16) & 1u);           // RNE
  return (ushort)(u >> 16);
}
__device__ inline float bf2f(ushort h) {
  return __builtin_bit_cast(float, (unsigned)h << 16);
}

// async global->LDS, 16B per lane; LDS dest must be wave-uniform base
__device__ __forceinline__ void gload16(const void* g, void* l) {
  __builtin_amdgcn_global_load_lds(
      (const __attribute__((address_space(1))) void*)g,
      (__attribute__((address_space(3))) void*)l, 16, 0, 0);
}

// ---------------- bias pack ----------------
__global__ __launch_bounds__(256) void pack_bias(const float* __restrict__ bq,
                                                 const float* __restrict__ bk,
                                                 const float* __restrict__ bv,
                                                 float* __restrict__ bqkv) {
  int idx = blockIdx.x * 256 + threadIdx.x;   // < 6*2304
  int l = idx / 2304, j = idx % 2304;
  float v = (j < 768) ? bq[l * 768 + j]
          : (j < 1536) ? bk[l * 768 + j - 768]
                       : bv[l * 768 + j - 1536];
  bqkv[idx] = v;
}

// ---------------- merged 768x768 weight transpose: Wq/Wk/Wv/Wo in one launch ----------------
__global__ __launch_bounds__(256) void transpose_w4(const float* __restrict__ Wq,
                                                    const float* __restrict__ Wk,
                                                    const float* __restrict__ Wv,
                                                    const float* __restrict__ Wo,
                                                    ushort* __restrict__ qkvt,
                                                    ushort* __restrict__ wot) {
  int z = blockIdx.z;              // 0..23
  int l = z % 6, w = z / 6;        // layer, weight selector
  const float* src = ((w == 0) ? Wq : (w == 1) ? Wk : (w == 2) ? Wv : Wo)
                     + (size_t)l * 768 * 768;
  ushort* dst = (w < 3) ? qkvt + (size_t)l * 2304 * 768 + (size_t)w * 768 * 768
                        : wot + (size_t)l * 768 * 768;
  __shared__ float t[32][33];
  int tx = threadIdx.x & 31, ty = threadIdx.x >> 5;
  int kb = blockIdx.x * 32, nb = blockIdx.y * 32;
#pragma unroll
  for (int i = 0; i < 4; i++) {
    int kr = ty + i * 8;
    t[kr][tx] = src[(long)(kb + kr) * 768 + nb + tx];
  }
  __syncthreads();
#pragma unroll
  for (int i = 0; i < 4; i++) {
    int nr = ty + i * 8;
    dst[(long)(nb + nr) * 768 + kb + tx] = f2bf(t[tx][nr]);
  }
}

// ---------------- weight transpose f32[K][N] -> bf16[N][K] (FF weights) ----------------
__global__ __launch_bounds__(256) void transpose_w(const float* __restrict__ src,
                                                   ushort* __restrict__ dst,
                                                   int K, int Nn,
                                                   long sstride, long dstride) {
  src += (long)blockIdx.z * sstride;
  dst += (long)blockIdx.z * dstride;
  __shared__ float t[32][33];
  int tx = threadIdx.x & 31, ty = threadIdx.x >> 5;
  int kb = blockIdx.x * 32, nb = blockIdx.y * 32;
#pragma unroll
  for (int i = 0; i < 4; i++) {
    int kr = ty + i * 8;
    t[kr][tx] = src[(long)(kb + kr) * Nn + nb + tx];
  }
  __syncthreads();
#pragma unroll
  for (int i = 0; i < 4; i++) {
    int nr = ty + i * 8;
    dst[(long)(nb + nr) * K + kb + tx] = f2bf(t[tx][nr]);
  }
}

// ---------------- embed: xb = bf16(concat(cls,x) + pos) ----------------
__global__ __launch_bounds__(256) void embed_k(const float* __restrict__ x,
                                               const float* __restrict__ pos,
                                               const float* __restrict__ cls,
                                               ushort* __restrict__ xb) {
  int idx = blockIdx.x * 256 + threadIdx.x;   // < 8192*192
  int c4 = idx % 192;
  int row = idx / 192;
  int t = row & 1023, n = row >> 10;
  f32x4 pv = ((const f32x4*)pos)[t * 192 + c4];
  f32x4 xv;
  if (t == 0) xv = ((const f32x4*)cls)[c4];
  else        xv = ((const f32x4*)x)[(size_t)(n * 1023 + t - 1) * 192 + c4];
  f32x4 s = xv + pv;
  ushort4 h;
  h.x = f2bf(s[0]); h.y = f2bf(s[1]); h.z = f2bf(s[2]); h.w = f2bf(s[3]);
  ((ushort4*)xb)[idx] = h;
}

// ---------------- 128^2 2-phase GEMM (5 blocks/CU: LDS-exact TLP) ----------------
// MODE 0: QKV — cols <1536 -> bf16 out16; cols >=1536 (V) -> vtb[n][h][d][t]
// MODE 2: out16 = bf16(gelu(acc + bias))          (FF1)
// MODE 3: split-K partial (S=2): slice z -> sp[z] (bf16)
template <int MODE>
__global__ __launch_bounds__(256, 5) void gemm_bt(const ushort* __restrict__ A,
                                                  const ushort* __restrict__ Bt,
                                                  int M, int N, int K,
                                                  const float* __restrict__ bias,
                                                  ushort* __restrict__ sp0,
                                                  ushort* __restrict__ sp1,
                                                  ushort* __restrict__ out16,
                                                  ushort* __restrict__ vtb,
                                                  int ksl) {
  __shared__ ushort As[128 * 64];
  __shared__ ushort Bs[128 * 64];
  int tid = threadIdx.x;
  int wid = tid >> 6, lane = tid & 63;
  int wm = wid >> 1, wn = wid & 1;
  int l15 = lane & 15, lhi = lane >> 4;
  int ln8 = lane >> 3, lc8 = (lane & 7) * 8;
  int row0 = blockIdx.x * 128, col0 = blockIdx.y * 128;
  int kb = (MODE == 3) ? blockIdx.z * ksl : 0;
  int nt = ((MODE == 3) ? ksl : K) >> 6;

  f32x4 acc[4][4];
#pragma unroll
  for (int i = 0; i < 4; i++)
#pragma unroll
    for (int j = 0; j < 4; j++) acc[i][j] = (f32x4){0.f, 0.f, 0.f, 0.f};

  const ushort* Ap = A + (size_t)(row0 + wid * 32 + ln8) * K + kb + lc8;
  const ushort* Bp = Bt + (size_t)(col0 + wid * 32 + ln8) * K + kb + lc8;

  for (int kt = 0; kt < nt; ++kt) {
    int k0 = kt << 6;
#pragma unroll
    for (int p = 0; p < 4; p++) {
      int r = wid * 32 + p * 8;
      gload16(Ap + (size_t)p * 8 * K + k0, As + r * 64);
      gload16(Bp + (size_t)p * 8 * K + k0, Bs + r * 64);
    }
    __syncthreads();
#pragma unroll
    for (int ks = 0; ks < 2; ks++) {
      bh8 af[4], bfr[4];
#pragma unroll
      for (int i = 0; i < 4; i++)
        af[i] = *(const bh8*)(As + (wm * 64 + i * 16 + l15) * 64 + ks * 32 + lhi * 8);
#pragma unroll
      for (int j = 0; j < 4; j++)
        bfr[j] = *(const bh8*)(Bs + (wn * 64 + j * 16 + l15) * 64 + ks * 32 + lhi * 8);
#pragma unroll
      for (int i = 0; i < 4; i++)
#pragma unroll
        for (int j = 0; j < 4; j++)
          acc[i][j] = __builtin_amdgcn_mfma_f32_16x16x32_bf16(af[i], bfr[j], acc[i][j], 0, 0, 0);
    }
    __syncthreads();
  }

  ushort* outp = nullptr;
  if (MODE == 3) outp = (blockIdx.z == 0) ? sp0 : sp1;
#pragma unroll
  for (int j = 0; j < 4; j++) {
    int col = col0 + wn * 64 + j * 16 + l15;
    float bv = (MODE == 3) ? 0.f : bias[col];
#pragma unroll
    for (int i = 0; i < 4; i++) {
      int rbase = row0 + wm * 64 + i * 16 + lhi * 4;
      if (MODE == 0 && col >= 1536) {
        int hd = col - 1536;
        int nn = rbase >> 10, t0 = rbase & 1023;
        ushort4 h4;
        h4.x = f2bf(acc[i][j][0] + bv);
        h4.y = f2bf(acc[i][j][1] + bv);
        h4.z = f2bf(acc[i][j][2] + bv);
        h4.w = f2bf(acc[i][j][3] + bv);
        *(ushort4*)(vtb + ((size_t)nn * 768 + hd) * 1024 + t0) = h4;
      } else {
#pragma unroll
        for (int r = 0; r < 4; r++) {
          int row = rbase + r;
          size_t o = (size_t)row * N + col;
          float v = acc[i][j][r] + bv;
          if (MODE == 0) {
            out16[o] = f2bf(v);
          } else if (MODE == 3) {
            outp[o] = f2bf(v);
          } else {
            v = 0.5f * v * (1.f + erff(v * 0.70710678118f));
            out16[o] = f2bf(v);
          }
        }
      }
    }
  }
}

// ======== 256^2 8-phase split-K GEMM (FF2 only), bf16 partials ========
__global__ __launch_bounds__(512, 1) void gemm256s(const ushort* __restrict__ A,
                                                   const ushort* __restrict__ Bt,
                                                   int M, int N, int K,
                                                   ushort* __restrict__ sp0,
                                                   ushort* __restrict__ sp1,
                                                   int ksl) {
  extern __shared__ ushort smem[];   // A slots @0, B slots @32768 (elems)
  int tid = threadIdx.x;
  int wid = tid >> 6, lane = tid & 63;
  int wr = wid >> 2, wc = wid & 3;
  int l15 = lane & 15, lhi = lane >> 4;
  int x7 = l15 & 7;
  int row0 = blockIdx.x * 256, col0 = blockIdx.y * 256;
  int kb = blockIdx.z * ksl;
  int nt = ksl >> 6;

  int srow = tid >> 3;                               // 0..63
  int swk = ((tid & 7) ^ (srow & 7)) << 3;           // pre-swizzled k offset
  const ushort* Ag = A + (size_t)(row0 + srow) * K + kb + swk;
  const ushort* Bg = Bt + (size_t)(col0 + srow) * K + kb + swk;

  auto stA = [&](int slot, int kt, int half) {
#pragma unroll
    for (int it = 0; it < 2; ++it) {
      int gr0 = half * 128 + it * 64;
      gload16(Ag + (size_t)gr0 * K + (size_t)kt * 64,
              smem + (slot << 14) + (gr0 + wid * 8) * 64);
    }
  };
  auto stB = [&](int slot, int kt, int half) {
#pragma unroll
    for (int it = 0; it < 2; ++it) {
      int gr0 = half * 128 + it * 64;
      gload16(Bg + (size_t)gr0 * K + (size_t)kt * 64,
              smem + 32768 + (slot << 14) + (gr0 + wid * 8) * 64);
    }
  };

  f32x4 acc[8][4];
#pragma unroll
  for (int i = 0; i < 8; i++)
#pragma unroll
    for (int j = 0; j < 4; j++) acc[i][j] = (f32x4){0.f, 0.f, 0.f, 0.f};

  stB(0, 0, 0); stB(0, 0, 1);
  stA(0, 0, 0); stA(0, 0, 1);
  stB(1, 1, 0); stB(1, 1, 1);

  bh8 bfr[4][2];

  for (int t = 0; t < nt; ++t) {
    int s = t & 1;
    const ushort* Ab = smem + (s << 14);
    const ushort* Bb = smem + 32768 + (s << 14);

    if (t + 1 < nt) {
      stA(s ^ 1, t + 1, 0);
      asm volatile("s_waitcnt vmcnt(6)" ::: "memory");
    } else {
      asm volatile("s_waitcnt vmcnt(0)" ::: "memory");
    }
    __builtin_amdgcn_s_barrier();

#pragma unroll
    for (int j = 0; j < 4; ++j)
#pragma unroll
      for (int kk = 0; kk < 2; ++kk)
        bfr[j][kk] = *(const bh8*)(Bb + (wc * 64 + j * 16 + l15) * 64 +
                                   (((kk * 4 + lhi) ^ x7) << 3));
    {
      bh8 af[2][2];
#pragma unroll
      for (int il = 0; il < 2; ++il)
#pragma unroll
        for (int kk = 0; kk < 2; ++kk)
          af[il][kk] = *(const bh8*)(Ab + (wr * 128 + il * 16 + l15) * 64 +
                                     (((kk * 4 + lhi) ^ x7) << 3));
      __builtin_amdgcn_s_setprio(1);
#pragma unroll
      for (int il = 0; il < 2; ++il)
#pragma unroll
        for (int j = 0; j < 4; ++j)
#pragma unroll
          for (int kk = 0; kk < 2; ++kk)
            acc[il][j] = __builtin_amdgcn_mfma_f32_16x16x32_bf16(
                af[il][kk], bfr[j][kk], acc[il][j], 0, 0, 0);
      __builtin_amdgcn_s_setprio(0);
    }
    asm volatile("s_waitcnt lgkmcnt(0)" ::: "memory");
    __builtin_amdgcn_s_barrier();

    if (t + 1 < nt) stA(s ^ 1, t + 1, 1);
    if (t + 2 < nt) stB(s, t + 2, 0);
#pragma unroll
    for (int q = 1; q < 4; ++q) {
      if (q == 2 && t + 2 < nt) stB(s, t + 2, 1);
      bh8 af[2][2];
#pragma unroll
      for (int il = 0; il < 2; ++il)
#pragma unroll
        for (int kk = 0; kk < 2; ++kk)
          af[il][kk] = *(const bh8*)(Ab + (wr * 128 + (q * 2 + il) * 16 + l15) * 64 +
                                     (((kk * 4 + lhi) ^ x7) << 3));
      __builtin_amdgcn_s_setprio(1);
#pragma unroll
      for (int il = 0; il < 2; ++il)
#pragma unroll
        for (int j = 0; j < 4; ++j)
#pragma unroll
          for (int kk = 0; kk < 2; ++kk)
            acc[q * 2 + il][j] = __builtin_amdgcn_mfma_f32_16x16x32_bf16(
                af[il][kk], bfr[j][kk], acc[q * 2 + il][j], 0, 0, 0);
      __builtin_amdgcn_s_setprio(0);
    }
  }

  ushort* outp = (blockIdx.z == 0) ? sp0 : sp1;
#pragma unroll
  for (int j = 0; j < 4; j++) {
    int col = col0 + wc * 64 + j * 16 + l15;
#pragma unroll
    for (int i = 0; i < 8; i++) {
      int rbase = row0 + wr * 128 + i * 16 + lhi * 4;
#pragma unroll
      for (int r = 0; r < 4; r++) {
        size_t o = (size_t)(rbase + r) * N + col;
        outp[o] = f2bf(acc[i][j][r]);
      }
    }
  }
}

// ---------------- flash attention, QBLK=128 (8 waves) ----------------
__global__ __launch_bounds__(512) void attn_k(const ushort* __restrict__ qkv,
                                              const ushort* __restrict__ vtb,
                                              const int* __restrict__ mask,
                                              ushort* __restrict__ attb) {
  int qt = blockIdx.x, h = blockIdx.y, n = blockIdx.z;
  int tid = threadIdx.x, wid = tid >> 6, lane = tid & 63;
  int l15 = lane & 15, lhi = lane >> 4;
  __shared__ ushort Ks[2][64 * 64];   // [kv][d], slot-swizzled
  __shared__ ushort Vs[2][64 * 64];   // [d][kv], slot-swizzled
  __shared__ ushort Pt[8][16 * 64];   // per-wave P, slot-swizzled
  ushort* Pw = Pt[wid];

  int ln8 = lane >> 3;
  int swc = (((lane & 7) ^ ln8) << 3);   // pre-swizzled source col (elems)

  const ushort* Kg = qkv + 768 + h * 64;
  const ushort* Vg = vtb + (size_t)(n * 768 + h * 64) * 1024;

  auto stage = [&](int b, int kv0) {
    int r = wid * 8;
    gload16(Kg + (size_t)(n * 1024 + kv0 + r + ln8) * 2304 + swc, &Ks[b][r * 64]);
    gload16(Vg + (size_t)(r + ln8) * 1024 + kv0 + swc, &Vs[b][r * 64]);
  };

  stage(0, 0);

  int q0 = qt * 128 + wid * 16;
  size_t rowQ = (size_t)(n * 1024 + q0 + l15) * 2304 + h * 64;
  bh8 qf0 = *(const bh8*)(qkv + rowQ + lhi * 8);
  bh8 qf1 = *(const bh8*)(qkv + rowQ + 32 + lhi * 8);

  unsigned long long mbits = 0ull;
#pragma unroll
  for (int i = 0; i < 64; ++i)
    mbits |= (unsigned long long)(mask[n * 1024 + i * 16 + l15] != 0) << i;

  bh8 ones;
#pragma unroll
  for (int i = 0; i < 8; ++i) ones[i] = (short)0x3F80;

  f32x4 o[4], lacc = (f32x4){0.f, 0.f, 0.f, 0.f};
#pragma unroll
  for (int i = 0; i < 4; i++) o[i] = (f32x4){0.f, 0.f, 0.f, 0.f};

  int x15 = (l15 & 7) << 3;
  int buf = 0;
  for (int t = 0; t < 16; ++t) {
    if (t < 15) {
      stage(buf ^ 1, (t + 1) * 64);
      asm volatile("s_waitcnt vmcnt(2)" ::: "memory");
    } else {
      asm volatile("s_waitcnt vmcnt(0)" ::: "memory");
    }
    __builtin_amdgcn_s_barrier();
    const ushort* Kb = Ks[buf];
    const ushort* Vb = Vs[buf];

    f32x4 s[4];
    __builtin_amdgcn_s_setprio(1);
#pragma unroll
    for (int t4 = 0; t4 < 4; ++t4) {
      int rs = (t4 * 16 + l15) * 64;
      s[t4] = (f32x4){0.f, 0.f, 0.f, 0.f};
      s[t4] = __builtin_amdgcn_mfma_f32_16x16x32_bf16(qf0, *(const bh8*)(Kb + rs + ((lhi << 3) ^ x15)), s[t4], 0, 0, 0);
      s[t4] = __builtin_amdgcn_mfma_f32_16x16x32_bf16(qf1, *(const bh8*)(Kb + rs + (((4 + lhi) << 3) ^ x15)), s[t4], 0, 0, 0);
    }
    __builtin_amdgcn_s_setprio(0);

#pragma unroll
    for (int t4 = 0; t4 < 4; ++t4) {
      bool mk = (mbits >> (t * 4 + t4)) & 1ull;
#pragma unroll
      for (int r = 0; r < 4; r++) {
        float xv = mk ? s[t4][r] * 0.125f : -1e20f;
        float p = __expf(fminf(xv, 80.f));
        int prow = lhi * 4 + r;
        int slot = t4 * 2 + (l15 >> 3);
        Pw[prow * 64 + (((slot ^ (prow & 7)) << 3) | (l15 & 7))] = f2bf(p);
      }
    }

    bh8 pf0 = *(const bh8*)(Pw + l15 * 64 + ((lhi << 3) ^ x15));
    bh8 pf1 = *(const bh8*)(Pw + l15 * 64 + (((4 + lhi) << 3) ^ x15));
    __builtin_amdgcn_s_setprio(1);
#pragma unroll
    for (int nb = 0; nb < 4; nb++) {
      int rs = (nb * 16 + l15) * 64;
      o[nb] = __builtin_amdgcn_mfma_f32_16x16x32_bf16(pf0, *(const bh8*)(Vb + rs + ((lhi << 3) ^ x15)), o[nb], 0, 0, 0);
      o[nb] = __builtin_amdgcn_mfma_f32_16x16x32_bf16(pf1, *(const bh8*)(Vb + rs + (((4 + lhi) << 3) ^ x15)), o[nb], 0, 0, 0);
    }
    lacc = __builtin_amdgcn_mfma_f32_16x16x32_bf16(pf0, ones, lacc, 0, 0, 0);
    lacc = __builtin_amdgcn_mfma_f32_16x16x32_bf16(pf1, ones, lacc, 0, 0, 0);
    __builtin_amdgcn_s_setprio(0);

    if (t < 15) {
      asm volatile("s_waitcnt lgkmcnt(0)" ::: "memory");
      __builtin_amdgcn_s_barrier();
    }
    buf ^= 1;
  }

#pragma unroll
  for (int nb = 0; nb < 4; nb++)
#pragma unroll
    for (int r = 0; r < 4; r++) {
      float val = o[nb][r] / lacc[r];
      int row = q0 + lhi * 4 + r;
      int col = h * 64 + nb * 16 + l15;
      attb[(size_t)(n * 1024 + row) * 768 + col] = f2bf(val);
    }
}

// ---- fused split-K(2) reduce + bias + bf16 residual + LayerNorm (vectorized) ----
template <bool FINAL>
__global__ __launch_bounds__(192) void ln_red_k(const ushort* __restrict__ p0,
                                                const ushort* __restrict__ p1,
                                                const ushort* __restrict__ resid,
                                                const float* __restrict__ bias,
                                                const float* __restrict__ g,
                                                const float* __restrict__ b,
                                                float* __restrict__ y32,
                                                ushort* __restrict__ y16) {
  int row = blockIdx.x, tid = threadIdx.x;
  int c = tid * 4;
  size_t base = (size_t)row * 768 + c;
  ushort4 r4 = *(const ushort4*)(resid + base);
  ushort4 a4 = *(const ushort4*)(p0 + base);
  ushort4 q4 = *(const ushort4*)(p1 + base);
  float4 bi = *(const float4*)(bias + c);
  float v[4];
  v[0] = bf2f(r4.x) + bf2f(a4.x) + bf2f(q4.x) + bi.x;
  v[1] = bf2f(r4.y) + bf2f(a4.y) + bf2f(q4.y) + bi.y;
  v[2] = bf2f(r4.z) + bf2f(a4.z) + bf2f(q4.z) + bi.z;
  v[3] = bf2f(r4.w) + bf2f(a4.w) + bf2f(q4.w) + bi.w;
  float s = v[0] + v[1] + v[2] + v[3];
  float sq = v[0] * v[0] + v[1] * v[1] + v[2] * v[2] + v[3] * v[3];
#pragma unroll
  for (int off = 32; off > 0; off >>= 1) {
    s += __shfl_down(s, off);
    sq += __shfl_down(sq, off);
  }
  __shared__ float sws[3], swq[3];
  int wd = tid >> 6, lane = tid & 63;
  if (lane == 0) { sws[wd] = s; swq[wd] = sq; }
  __syncthreads();
  float ts = sws[0] + sws[1] + sws[2];
  float tq = swq[0] + swq[1] + swq[2];
  float mean = ts * (1.f / 768.f);
  float var = tq * (1.f / 768.f) - mean * mean;
  float rstd = rsqrtf(var + 1e-5f);
  float4 g4 = *(const float4*)(g + c);
  float4 b4 = *(const float4*)(b + c);
  float y0 = (v[0] - mean) * rstd * g4.x + b4.x;
  float y1 = (v[1] - mean) * rstd * g4.y + b4.y;
  float y2 = (v[2] - mean) * rstd * g4.z + b4.z;
  float y3 = (v[3] - mean) * rstd * g4.w + b4.w;
  if (FINAL) {
    *(float4*)(y32 + base) = make_float4(y0, y1, y2, y3);
  } else {
    ushort4 h;
    h.x = f2bf(y0); h.y = f2bf(y1); h.z = f2bf(y2); h.w = f2bf(y3);
    *(ushort4*)(y16 + base) = h;
  }
}

extern "C" void kernel_launch(void* const* d_in, const int* in_sizes, int n_in,
                              void* d_out, int out_size, void* d_ws, size_t ws_size,
                              hipStream_t stream) {
  const float* x    = (const float*)d_in[0];
  const int*   mask = (const int*)d_in[1];
  const float* pos  = (const float*)d_in[2];
  const float* cls  = (const float*)d_in[3];
  const float* Wq   = (const float*)d_in[4];
  const float* bq   = (const float*)d_in[5];
  const float* Wk   = (const float*)d_in[6];
  const float* bk   = (const float*)d_in[7];
  const float* Wv   = (const float*)d_in[8];
  const float* bv   = (const float*)d_in[9];
  const float* Wo   = (const float*)d_in[10];
  const float* bo   = (const float*)d_in[11];
  const float* ln1g = (const float*)d_in[12];
  const float* ln1b = (const float*)d_in[13];
  const float* ln2g = (const float*)d_in[14];
  const float* ln2b = (const float*)d_in[15];
  const float* Wf1  = (const float*)d_in[16];
  const float* bf1  = (const float*)d_in[17];
  const float* Wf2  = (const float*)d_in[18];
  const float* bf2w = (const float*)d_in[19];

  hipFuncSetAttribute(reinterpret_cast<const void*>(gemm256s),
                      hipFuncAttributeMaxDynamicSharedMemorySize, 131072);

  char* ws = (char*)d_ws;
  size_t off = 0;
  auto alloc = [&](size_t bytes) {
    char* p = ws + off;
    off += (bytes + 255) & ~(size_t)255;
    return p;
  };
  const size_t M = 8192;
  ushort* qkvt = (ushort*)alloc((size_t)L_ * 2304 * 768 * 2);
  ushort* wot  = (ushort*)alloc((size_t)L_ * 768 * 768 * 2);
  ushort* wf1t = (ushort*)alloc((size_t)L_ * 3072 * 768 * 2);
  ushort* wf2t = (ushort*)alloc((size_t)L_ * 768 * 3072 * 2);
  float*  bqkv = (float*)alloc((size_t)L_ * 2304 * 4);
  ushort* xb   = (ushort*)alloc(M * 768 * 2);
  ushort* qkvb = (ushort*)alloc(M * 2304 * 2);
  ushort* vtb  = (ushort*)alloc(M * 768 * 2);
  ushort* attb = (ushort*)alloc(M * 768 * 2);
  ushort* ffb  = (ushort*)alloc(M * 3072 * 2);
  ushort* slA  = (ushort*)alloc(M * 768 * 2 * 2);   // 2 bf16 split-K slices
  ushort* slB  = slA + M * 768;
  (void)ws_size; (void)in_sizes; (void)n_in; (void)out_size;

  dim3 tb(256);
  pack_bias<<<54, tb, 0, stream>>>(bq, bk, bv, bqkv);
  transpose_w4<<<dim3(24, 24, 24), tb, 0, stream>>>(Wq, Wk, Wv, Wo, qkvt, wot);
  transpose_w<<<dim3(24, 96, 6), tb, 0, stream>>>(Wf1, wf1t, 768, 3072, 768L * 3072, 3072L * 768);
  transpose_w<<<dim3(96, 24, 6), tb, 0, stream>>>(Wf2, wf2t, 3072, 768, 3072L * 768, 768L * 3072);
  embed_k<<<6144, tb, 0, stream>>>(x, pos, cls, xb);

  for (int l = 0; l < L_; l++) {
    // QKV: 128^2 2-phase
    gemm_bt<0><<<dim3(64, 18), tb, 0, stream>>>(xb, qkvt + (size_t)l * 2304 * 768,
                                                8192, 2304, 768, bqkv + l * 2304,
                                                nullptr, nullptr, qkvb, vtb, 0);
    // attn: QBLK=128, 8 waves
    attn_k<<<dim3(8, 12, 8), dim3(512), 0, stream>>>(qkvb, vtb, mask, attb);
    // Wo: 128^2 2-phase split-K S=2 (ksl=384, 768 blocks = 3/CU), bf16 partials
    gemm_bt<3><<<dim3(64, 6, 2), tb, 0, stream>>>(attb, wot + (size_t)l * 768 * 768,
                                                  8192, 768, 768, nullptr,
                                                  slA, slB, nullptr, nullptr, 384);
    // ln1: resid = xb (layer input), writes xb (hid)
    ln_red_k<false><<<8192, dim3(192), 0, stream>>>(slA, slB, xb, bo + l * 768,
                                                    ln1g + l * 768, ln1b + l * 768,
                                                    nullptr, xb);
    // FF1: 128^2 2-phase (gelu)
    gemm_bt<2><<<dim3(64, 24), tb, 0, stream>>>(xb, wf1t + (size_t)l * 3072 * 768,
                                                8192, 3072, 768, bf1 + l * 3072,
                                                nullptr, nullptr, ffb, nullptr, 0);
    // FF2: 256^2 8-phase split-K S=2 (ksl=1536), bf16 partials
    gemm256s<<<dim3(32, 3, 2), 512, 131072, stream>>>(ffb, wf2t + (size_t)l * 768 * 3072,
                                                      8192, 768, 3072,
                                                      slA, slB, 1536);
    // ln2: resid = xb (hid), writes xb (out) or final f32 d_out
    if (l < L_ - 1) {
      ln_red_k<false><<<8192, dim3(192), 0, stream>>>(slA, slB, xb, bf2w + l * 768,
                                                      ln2g + l * 768, ln2b + l * 768,
                                                      nullptr, xb);
    } else {
      ln_red_k<true><<<8192, dim3(192), 0, stream>>>(slA, slB, xb, bf2w + l * 768,
                                                     ln2g + l * 768, ln2b + l * 768,
                                                     (float*)d_out, nullptr);
    }
  }
}

// Round 17
// 1634.255 us; speedup vs baseline: 1.2745x; 1.2745x over previous
//
#include <hip/hip_runtime.h>

#define L_ 6
#define E_ 768
#define H_ 12
#define FF_ 3072

typedef __attribute__((ext_vector_type(8))) short bh8;     // 8 bf16 (4 VGPRs)
typedef __attribute__((ext_vector_type(4))) float f32x4;

__device__ inline ushort f2bf(float f) {
  unsigned u = __builtin_bit_cast(unsigned, f);
  u += 0x7fffu + ((u >> 16) & 1u);           // RNE
  return (ushort)(u >> 16);
}
__device__ inline float bf2f(ushort h) {
  return __builtin_bit_cast(float, (unsigned)h << 16);
}

// async global->LDS, 16B per lane; LDS dest must be wave-uniform base
__device__ __forceinline__ void gload16(const void* g, void* l) {
  __builtin_amdgcn_global_load_lds(
      (const __attribute__((address_space(1))) void*)g,
      (__attribute__((address_space(3))) void*)l, 16, 0, 0);
}

// ---------------- bias pack ----------------
__global__ __launch_bounds__(256) void pack_bias(const float* __restrict__ bq,
                                                 const float* __restrict__ bk,
                                                 const float* __restrict__ bv,
                                                 float* __restrict__ bqkv) {
  int idx = blockIdx.x * 256 + threadIdx.x;   // < 6*2304
  int l = idx / 2304, j = idx % 2304;
  float v = (j < 768) ? bq[l * 768 + j]
          : (j < 1536) ? bk[l * 768 + j - 768]
                       : bv[l * 768 + j - 1536];
  bqkv[idx] = v;
}

// ---------------- merged 768x768 weight transpose: Wq/Wk/Wv/Wo in one launch ----------------
__global__ __launch_bounds__(256) void transpose_w4(const float* __restrict__ Wq,
                                                    const float* __restrict__ Wk,
                                                    const float* __restrict__ Wv,
                                                    const float* __restrict__ Wo,
                                                    ushort* __restrict__ qkvt,
                                                    ushort* __restrict__ wot) {
  int z = blockIdx.z;              // 0..23
  int l = z % 6, w = z / 6;        // layer, weight selector
  const float* src = ((w == 0) ? Wq : (w == 1) ? Wk : (w == 2) ? Wv : Wo)
                     + (size_t)l * 768 * 768;
  ushort* dst = (w < 3) ? qkvt + (size_t)l * 2304 * 768 + (size_t)w * 768 * 768
                        : wot + (size_t)l * 768 * 768;
  __shared__ float t[32][33];
  int tx = threadIdx.x & 31, ty = threadIdx.x >> 5;
  int kb = blockIdx.x * 32, nb = blockIdx.y * 32;
#pragma unroll
  for (int i = 0; i < 4; i++) {
    int kr = ty + i * 8;
    t[kr][tx] = src[(long)(kb + kr) * 768 + nb + tx];
  }
  __syncthreads();
#pragma unroll
  for (int i = 0; i < 4; i++) {
    int nr = ty + i * 8;
    dst[(long)(nb + nr) * 768 + kb + tx] = f2bf(t[tx][nr]);
  }
}

// ---------------- weight transpose f32[K][N] -> bf16[N][K] (FF weights) ----------------
__global__ __launch_bounds__(256) void transpose_w(const float* __restrict__ src,
                                                   ushort* __restrict__ dst,
                                                   int K, int Nn,
                                                   long sstride, long dstride) {
  src += (long)blockIdx.z * sstride;
  dst += (long)blockIdx.z * dstride;
  __shared__ float t[32][33];
  int tx = threadIdx.x & 31, ty = threadIdx.x >> 5;
  int kb = blockIdx.x * 32, nb = blockIdx.y * 32;
#pragma unroll
  for (int i = 0; i < 4; i++) {
    int kr = ty + i * 8;
    t[kr][tx] = src[(long)(kb + kr) * Nn + nb + tx];
  }
  __syncthreads();
#pragma unroll
  for (int i = 0; i < 4; i++) {
    int nr = ty + i * 8;
    dst[(long)(nb + nr) * K + kb + tx] = f2bf(t[tx][nr]);
  }
}

// ---------------- embed: xb = bf16(concat(cls,x) + pos) ----------------
__global__ __launch_bounds__(256) void embed_k(const float* __restrict__ x,
                                               const float* __restrict__ pos,
                                               const float* __restrict__ cls,
                                               ushort* __restrict__ xb) {
  int idx = blockIdx.x * 256 + threadIdx.x;   // < 8192*192
  int c4 = idx % 192;
  int row = idx / 192;
  int t = row & 1023, n = row >> 10;
  f32x4 pv = ((const f32x4*)pos)[t * 192 + c4];
  f32x4 xv;
  if (t == 0) xv = ((const f32x4*)cls)[c4];
  else        xv = ((const f32x4*)x)[(size_t)(n * 1023 + t - 1) * 192 + c4];
  f32x4 s = xv + pv;
  ushort4 h;
  h.x = f2bf(s[0]); h.y = f2bf(s[1]); h.z = f2bf(s[2]); h.w = f2bf(s[3]);
  ((ushort4*)xb)[idx] = h;
}

// ---------------- 128^2 2-phase GEMM ----------------
// MODE 0: QKV — cols <1536 -> bf16 out16; cols >=1536 (V) -> vtb[n][h][d][t]
// MODE 2: out16 = bf16(gelu(acc + bias))          (FF1)
// MODE 3: split-K partial (S=2): slice z -> sp[z] (bf16)
template <int MODE>
__global__ __launch_bounds__(256, 4) void gemm_bt(const ushort* __restrict__ A,
                                                  const ushort* __restrict__ Bt,
                                                  int M, int N, int K,
                                                  const float* __restrict__ bias,
                                                  ushort* __restrict__ sp0,
                                                  ushort* __restrict__ sp1,
                                                  ushort* __restrict__ out16,
                                                  ushort* __restrict__ vtb,
                                                  int ksl) {
  __shared__ ushort As[128 * 64];
  __shared__ ushort Bs[128 * 64];
  int tid = threadIdx.x;
  int wid = tid >> 6, lane = tid & 63;
  int wm = wid >> 1, wn = wid & 1;
  int l15 = lane & 15, lhi = lane >> 4;
  int ln8 = lane >> 3, lc8 = (lane & 7) * 8;
  int row0 = blockIdx.x * 128, col0 = blockIdx.y * 128;
  int kb = (MODE == 3) ? blockIdx.z * ksl : 0;
  int nt = ((MODE == 3) ? ksl : K) >> 6;

  f32x4 acc[4][4];
#pragma unroll
  for (int i = 0; i < 4; i++)
#pragma unroll
    for (int j = 0; j < 4; j++) acc[i][j] = (f32x4){0.f, 0.f, 0.f, 0.f};

  const ushort* Ap = A + (size_t)(row0 + wid * 32 + ln8) * K + kb + lc8;
  const ushort* Bp = Bt + (size_t)(col0 + wid * 32 + ln8) * K + kb + lc8;

  for (int kt = 0; kt < nt; ++kt) {
    int k0 = kt << 6;
#pragma unroll
    for (int p = 0; p < 4; p++) {
      int r = wid * 32 + p * 8;
      gload16(Ap + (size_t)p * 8 * K + k0, As + r * 64);
      gload16(Bp + (size_t)p * 8 * K + k0, Bs + r * 64);
    }
    __syncthreads();
#pragma unroll
    for (int ks = 0; ks < 2; ks++) {
      bh8 af[4], bfr[4];
#pragma unroll
      for (int i = 0; i < 4; i++)
        af[i] = *(const bh8*)(As + (wm * 64 + i * 16 + l15) * 64 + ks * 32 + lhi * 8);
#pragma unroll
      for (int j = 0; j < 4; j++)
        bfr[j] = *(const bh8*)(Bs + (wn * 64 + j * 16 + l15) * 64 + ks * 32 + lhi * 8);
#pragma unroll
      for (int i = 0; i < 4; i++)
#pragma unroll
        for (int j = 0; j < 4; j++)
          acc[i][j] = __builtin_amdgcn_mfma_f32_16x16x32_bf16(af[i], bfr[j], acc[i][j], 0, 0, 0);
    }
    __syncthreads();
  }

  ushort* outp = nullptr;
  if (MODE == 3) outp = (blockIdx.z == 0) ? sp0 : sp1;
#pragma unroll
  for (int j = 0; j < 4; j++) {
    int col = col0 + wn * 64 + j * 16 + l15;
    float bv = (MODE == 3) ? 0.f : bias[col];
#pragma unroll
    for (int i = 0; i < 4; i++) {
      int rbase = row0 + wm * 64 + i * 16 + lhi * 4;
      if (MODE == 0 && col >= 1536) {
        int hd = col - 1536;
        int nn = rbase >> 10, t0 = rbase & 1023;
        ushort4 h4;
        h4.x = f2bf(acc[i][j][0] + bv);
        h4.y = f2bf(acc[i][j][1] + bv);
        h4.z = f2bf(acc[i][j][2] + bv);
        h4.w = f2bf(acc[i][j][3] + bv);
        *(ushort4*)(vtb + ((size_t)nn * 768 + hd) * 1024 + t0) = h4;
      } else {
#pragma unroll
        for (int r = 0; r < 4; r++) {
          int row = rbase + r;
          size_t o = (size_t)row * N + col;
          float v = acc[i][j][r] + bv;
          if (MODE == 0) {
            out16[o] = f2bf(v);
          } else if (MODE == 3) {
            outp[o] = f2bf(v);
          } else {
            v = 0.5f * v * (1.f + erff(v * 0.70710678118f));
            out16[o] = f2bf(v);
          }
        }
      }
    }
  }
}

// ======== 256^2 8-phase split-K GEMM (FF2 only), bf16 partials ========
__global__ __launch_bounds__(512, 1) void gemm256s(const ushort* __restrict__ A,
                                                   const ushort* __restrict__ Bt,
                                                   int M, int N, int K,
                                                   ushort* __restrict__ sp0,
                                                   ushort* __restrict__ sp1,
                                                   int ksl) {
  extern __shared__ ushort smem[];   // A slots @0, B slots @32768 (elems)
  int tid = threadIdx.x;
  int wid = tid >> 6, lane = tid & 63;
  int wr = wid >> 2, wc = wid & 3;
  int l15 = lane & 15, lhi = lane >> 4;
  int x7 = l15 & 7;
  int row0 = blockIdx.x * 256, col0 = blockIdx.y * 256;
  int kb = blockIdx.z * ksl;
  int nt = ksl >> 6;

  int srow = tid >> 3;                               // 0..63
  int swk = ((tid & 7) ^ (srow & 7)) << 3;           // pre-swizzled k offset
  const ushort* Ag = A + (size_t)(row0 + srow) * K + kb + swk;
  const ushort* Bg = Bt + (size_t)(col0 + srow) * K + kb + swk;

  auto stA = [&](int slot, int kt, int half) {
#pragma unroll
    for (int it = 0; it < 2; ++it) {
      int gr0 = half * 128 + it * 64;
      gload16(Ag + (size_t)gr0 * K + (size_t)kt * 64,
              smem + (slot << 14) + (gr0 + wid * 8) * 64);
    }
  };
  auto stB = [&](int slot, int kt, int half) {
#pragma unroll
    for (int it = 0; it < 2; ++it) {
      int gr0 = half * 128 + it * 64;
      gload16(Bg + (size_t)gr0 * K + (size_t)kt * 64,
              smem + 32768 + (slot << 14) + (gr0 + wid * 8) * 64);
    }
  };

  f32x4 acc[8][4];
#pragma unroll
  for (int i = 0; i < 8; i++)
#pragma unroll
    for (int j = 0; j < 4; j++) acc[i][j] = (f32x4){0.f, 0.f, 0.f, 0.f};

  stB(0, 0, 0); stB(0, 0, 1);
  stA(0, 0, 0); stA(0, 0, 1);
  stB(1, 1, 0); stB(1, 1, 1);

  bh8 bfr[4][2];

  for (int t = 0; t < nt; ++t) {
    int s = t & 1;
    const ushort* Ab = smem + (s << 14);
    const ushort* Bb = smem + 32768 + (s << 14);

    if (t + 1 < nt) {
      stA(s ^ 1, t + 1, 0);
      asm volatile("s_waitcnt vmcnt(6)" ::: "memory");
    } else {
      asm volatile("s_waitcnt vmcnt(0)" ::: "memory");
    }
    __builtin_amdgcn_s_barrier();

#pragma unroll
    for (int j = 0; j < 4; ++j)
#pragma unroll
      for (int kk = 0; kk < 2; ++kk)
        bfr[j][kk] = *(const bh8*)(Bb + (wc * 64 + j * 16 + l15) * 64 +
                                   (((kk * 4 + lhi) ^ x7) << 3));
    {
      bh8 af[2][2];
#pragma unroll
      for (int il = 0; il < 2; ++il)
#pragma unroll
        for (int kk = 0; kk < 2; ++kk)
          af[il][kk] = *(const bh8*)(Ab + (wr * 128 + il * 16 + l15) * 64 +
                                     (((kk * 4 + lhi) ^ x7) << 3));
      __builtin_amdgcn_s_setprio(1);
#pragma unroll
      for (int il = 0; il < 2; ++il)
#pragma unroll
        for (int j = 0; j < 4; ++j)
#pragma unroll
          for (int kk = 0; kk < 2; ++kk)
            acc[il][j] = __builtin_amdgcn_mfma_f32_16x16x32_bf16(
                af[il][kk], bfr[j][kk], acc[il][j], 0, 0, 0);
      __builtin_amdgcn_s_setprio(0);
    }
    asm volatile("s_waitcnt lgkmcnt(0)" ::: "memory");
    __builtin_amdgcn_s_barrier();

    if (t + 1 < nt) stA(s ^ 1, t + 1, 1);
    if (t + 2 < nt) stB(s, t + 2, 0);
#pragma unroll
    for (int q = 1; q < 4; ++q) {
      if (q == 2 && t + 2 < nt) stB(s, t + 2, 1);
      bh8 af[2][2];
#pragma unroll
      for (int il = 0; il < 2; ++il)
#pragma unroll
        for (int kk = 0; kk < 2; ++kk)
          af[il][kk] = *(const bh8*)(Ab + (wr * 128 + (q * 2 + il) * 16 + l15) * 64 +
                                     (((kk * 4 + lhi) ^ x7) << 3));
      __builtin_amdgcn_s_setprio(1);
#pragma unroll
      for (int il = 0; il < 2; ++il)
#pragma unroll
        for (int j = 0; j < 4; ++j)
#pragma unroll
          for (int kk = 0; kk < 2; ++kk)
            acc[q * 2 + il][j] = __builtin_amdgcn_mfma_f32_16x16x32_bf16(
                af[il][kk], bfr[j][kk], acc[q * 2 + il][j], 0, 0, 0);
      __builtin_amdgcn_s_setprio(0);
    }
  }

  ushort* outp = (blockIdx.z == 0) ? sp0 : sp1;
#pragma unroll
  for (int j = 0; j < 4; j++) {
    int col = col0 + wc * 64 + j * 16 + l15;
#pragma unroll
    for (int i = 0; i < 8; i++) {
      int rbase = row0 + wr * 128 + i * 16 + lhi * 4;
#pragma unroll
      for (int r = 0; r < 4; r++) {
        size_t o = (size_t)(rbase + r) * N + col;
        outp[o] = f2bf(acc[i][j][r]);
      }
    }
  }
}

// ---------------- flash attention, QBLK=128 (8 waves) ----------------
__global__ __launch_bounds__(512) void attn_k(const ushort* __restrict__ qkv,
                                              const ushort* __restrict__ vtb,
                                              const int* __restrict__ mask,
                                              ushort* __restrict__ attb) {
  int qt = blockIdx.x, h = blockIdx.y, n = blockIdx.z;
  int tid = threadIdx.x, wid = tid >> 6, lane = tid & 63;
  int l15 = lane & 15, lhi = lane >> 4;
  __shared__ ushort Ks[2][64 * 64];   // [kv][d], slot-swizzled
  __shared__ ushort Vs[2][64 * 64];   // [d][kv], slot-swizzled
  __shared__ ushort Pt[8][16 * 64];   // per-wave P, slot-swizzled
  ushort* Pw = Pt[wid];

  int ln8 = lane >> 3;
  int swc = (((lane & 7) ^ ln8) << 3);   // pre-swizzled source col (elems)

  const ushort* Kg = qkv + 768 + h * 64;
  const ushort* Vg = vtb + (size_t)(n * 768 + h * 64) * 1024;

  auto stage = [&](int b, int kv0) {
    int r = wid * 8;
    gload16(Kg + (size_t)(n * 1024 + kv0 + r + ln8) * 2304 + swc, &Ks[b][r * 64]);
    gload16(Vg + (size_t)(r + ln8) * 1024 + kv0 + swc, &Vs[b][r * 64]);
  };

  stage(0, 0);

  int q0 = qt * 128 + wid * 16;
  size_t rowQ = (size_t)(n * 1024 + q0 + l15) * 2304 + h * 64;
  bh8 qf0 = *(const bh8*)(qkv + rowQ + lhi * 8);
  bh8 qf1 = *(const bh8*)(qkv + rowQ + 32 + lhi * 8);

  unsigned long long mbits = 0ull;
#pragma unroll
  for (int i = 0; i < 64; ++i)
    mbits |= (unsigned long long)(mask[n * 1024 + i * 16 + l15] != 0) << i;

  bh8 ones;
#pragma unroll
  for (int i = 0; i < 8; ++i) ones[i] = (short)0x3F80;

  f32x4 o[4], lacc = (f32x4){0.f, 0.f, 0.f, 0.f};
#pragma unroll
  for (int i = 0; i < 4; i++) o[i] = (f32x4){0.f, 0.f, 0.f, 0.f};

  int x15 = (l15 & 7) << 3;
  int buf = 0;
  for (int t = 0; t < 16; ++t) {
    if (t < 15) {
      stage(buf ^ 1, (t + 1) * 64);
      asm volatile("s_waitcnt vmcnt(2)" ::: "memory");
    } else {
      asm volatile("s_waitcnt vmcnt(0)" ::: "memory");
    }
    __builtin_amdgcn_s_barrier();
    const ushort* Kb = Ks[buf];
    const ushort* Vb = Vs[buf];

    f32x4 s[4];
    __builtin_amdgcn_s_setprio(1);
#pragma unroll
    for (int t4 = 0; t4 < 4; ++t4) {
      int rs = (t4 * 16 + l15) * 64;
      s[t4] = (f32x4){0.f, 0.f, 0.f, 0.f};
      s[t4] = __builtin_amdgcn_mfma_f32_16x16x32_bf16(qf0, *(const bh8*)(Kb + rs + ((lhi << 3) ^ x15)), s[t4], 0, 0, 0);
      s[t4] = __builtin_amdgcn_mfma_f32_16x16x32_bf16(qf1, *(const bh8*)(Kb + rs + (((4 + lhi) << 3) ^ x15)), s[t4], 0, 0, 0);
    }
    __builtin_amdgcn_s_setprio(0);

#pragma unroll
    for (int t4 = 0; t4 < 4; ++t4) {
      bool mk = (mbits >> (t * 4 + t4)) & 1ull;
#pragma unroll
      for (int r = 0; r < 4; r++) {
        float xv = mk ? s[t4][r] * 0.125f : -1e20f;
        float p = __expf(fminf(xv, 80.f));
        int prow = lhi * 4 + r;
        int slot = t4 * 2 + (l15 >> 3);
        Pw[prow * 64 + (((slot ^ (prow & 7)) << 3) | (l15 & 7))] = f2bf(p);
      }
    }

    bh8 pf0 = *(const bh8*)(Pw + l15 * 64 + ((lhi << 3) ^ x15));
    bh8 pf1 = *(const bh8*)(Pw + l15 * 64 + (((4 + lhi) << 3) ^ x15));
    __builtin_amdgcn_s_setprio(1);
#pragma unroll
    for (int nb = 0; nb < 4; nb++) {
      int rs = (nb * 16 + l15) * 64;
      o[nb] = __builtin_amdgcn_mfma_f32_16x16x32_bf16(pf0, *(const bh8*)(Vb + rs + ((lhi << 3) ^ x15)), o[nb], 0, 0, 0);
      o[nb] = __builtin_amdgcn_mfma_f32_16x16x32_bf16(pf1, *(const bh8*)(Vb + rs + (((4 + lhi) << 3) ^ x15)), o[nb], 0, 0, 0);
    }
    lacc = __builtin_amdgcn_mfma_f32_16x16x32_bf16(pf0, ones, lacc, 0, 0, 0);
    lacc = __builtin_amdgcn_mfma_f32_16x16x32_bf16(pf1, ones, lacc, 0, 0, 0);
    __builtin_amdgcn_s_setprio(0);

    if (t < 15) {
      asm volatile("s_waitcnt lgkmcnt(0)" ::: "memory");
      __builtin_amdgcn_s_barrier();
    }
    buf ^= 1;
  }

#pragma unroll
  for (int nb = 0; nb < 4; nb++)
#pragma unroll
    for (int r = 0; r < 4; r++) {
      float val = o[nb][r] / lacc[r];
      int row = q0 + lhi * 4 + r;
      int col = h * 64 + nb * 16 + l15;
      attb[(size_t)(n * 1024 + row) * 768 + col] = f2bf(val);
    }
}

// ---- fused split-K(2) reduce + bias + bf16 residual + LayerNorm (vectorized) ----
template <bool FINAL>
__global__ __launch_bounds__(192) void ln_red_k(const ushort* __restrict__ p0,
                                                const ushort* __restrict__ p1,
                                                const ushort* __restrict__ resid,
                                                const float* __restrict__ bias,
                                                const float* __restrict__ g,
                                                const float* __restrict__ b,
                                                float* __restrict__ y32,
                                                ushort* __restrict__ y16) {
  int row = blockIdx.x, tid = threadIdx.x;
  int c = tid * 4;
  size_t base = (size_t)row * 768 + c;
  ushort4 r4 = *(const ushort4*)(resid + base);
  ushort4 a4 = *(const ushort4*)(p0 + base);
  ushort4 q4 = *(const ushort4*)(p1 + base);
  float4 bi = *(const float4*)(bias + c);
  float v[4];
  v[0] = bf2f(r4.x) + bf2f(a4.x) + bf2f(q4.x) + bi.x;
  v[1] = bf2f(r4.y) + bf2f(a4.y) + bf2f(q4.y) + bi.y;
  v[2] = bf2f(r4.z) + bf2f(a4.z) + bf2f(q4.z) + bi.z;
  v[3] = bf2f(r4.w) + bf2f(a4.w) + bf2f(q4.w) + bi.w;
  float s = v[0] + v[1] + v[2] + v[3];
  float sq = v[0] * v[0] + v[1] * v[1] + v[2] * v[2] + v[3] * v[3];
#pragma unroll
  for (int off = 32; off > 0; off >>= 1) {
    s += __shfl_down(s, off);
    sq += __shfl_down(sq, off);
  }
  __shared__ float sws[3], swq[3];
  int wd = tid >> 6, lane = tid & 63;
  if (lane == 0) { sws[wd] = s; swq[wd] = sq; }
  __syncthreads();
  float ts = sws[0] + sws[1] + sws[2];
  float tq = swq[0] + swq[1] + swq[2];
  float mean = ts * (1.f / 768.f);
  float var = tq * (1.f / 768.f) - mean * mean;
  float rstd = rsqrtf(var + 1e-5f);
  float4 g4 = *(const float4*)(g + c);
  float4 b4 = *(const float4*)(b + c);
  float y0 = (v[0] - mean) * rstd * g4.x + b4.x;
  float y1 = (v[1] - mean) * rstd * g4.y + b4.y;
  float y2 = (v[2] - mean) * rstd * g4.z + b4.z;
  float y3 = (v[3] - mean) * rstd * g4.w + b4.w;
  if (FINAL) {
    *(float4*)(y32 + base) = make_float4(y0, y1, y2, y3);
  } else {
    ushort4 h;
    h.x = f2bf(y0); h.y = f2bf(y1); h.z = f2bf(y2); h.w = f2bf(y3);
    *(ushort4*)(y16 + base) = h;
  }
}

extern "C" void kernel_launch(void* const* d_in, const int* in_sizes, int n_in,
                              void* d_out, int out_size, void* d_ws, size_t ws_size,
                              hipStream_t stream) {
  const float* x    = (const float*)d_in[0];
  const int*   mask = (const int*)d_in[1];
  const float* pos  = (const float*)d_in[2];
  const float* cls  = (const float*)d_in[3];
  const float* Wq   = (const float*)d_in[4];
  const float* bq   = (const float*)d_in[5];
  const float* Wk   = (const float*)d_in[6];
  const float* bk   = (const float*)d_in[7];
  const float* Wv   = (const float*)d_in[8];
  const float* bv   = (const float*)d_in[9];
  const float* Wo   = (const float*)d_in[10];
  const float* bo   = (const float*)d_in[11];
  const float* ln1g = (const float*)d_in[12];
  const float* ln1b = (const float*)d_in[13];
  const float* ln2g = (const float*)d_in[14];
  const float* ln2b = (const float*)d_in[15];
  const float* Wf1  = (const float*)d_in[16];
  const float* bf1  = (const float*)d_in[17];
  const float* Wf2  = (const float*)d_in[18];
  const float* bf2w = (const float*)d_in[19];

  hipFuncSetAttribute(reinterpret_cast<const void*>(gemm256s),
                      hipFuncAttributeMaxDynamicSharedMemorySize, 131072);

  char* ws = (char*)d_ws;
  size_t off = 0;
  auto alloc = [&](size_t bytes) {
    char* p = ws + off;
    off += (bytes + 255) & ~(size_t)255;
    return p;
  };
  const size_t M = 8192;
  ushort* qkvt = (ushort*)alloc((size_t)L_ * 2304 * 768 * 2);
  ushort* wot  = (ushort*)alloc((size_t)L_ * 768 * 768 * 2);
  ushort* wf1t = (ushort*)alloc((size_t)L_ * 3072 * 768 * 2);
  ushort* wf2t = (ushort*)alloc((size_t)L_ * 768 * 3072 * 2);
  float*  bqkv = (float*)alloc((size_t)L_ * 2304 * 4);
  ushort* xb   = (ushort*)alloc(M * 768 * 2);
  ushort* qkvb = (ushort*)alloc(M * 2304 * 2);
  ushort* vtb  = (ushort*)alloc(M * 768 * 2);
  ushort* attb = (ushort*)alloc(M * 768 * 2);
  ushort* ffb  = (ushort*)alloc(M * 3072 * 2);
  ushort* slA  = (ushort*)alloc(M * 768 * 2 * 2);   // 2 bf16 split-K slices
  ushort* slB  = slA + M * 768;
  (void)ws_size; (void)in_sizes; (void)n_in; (void)out_size;

  dim3 tb(256);
  pack_bias<<<54, tb, 0, stream>>>(bq, bk, bv, bqkv);
  transpose_w4<<<dim3(24, 24, 24), tb, 0, stream>>>(Wq, Wk, Wv, Wo, qkvt, wot);
  transpose_w<<<dim3(24, 96, 6), tb, 0, stream>>>(Wf1, wf1t, 768, 3072, 768L * 3072, 3072L * 768);
  transpose_w<<<dim3(96, 24, 6), tb, 0, stream>>>(Wf2, wf2t, 3072, 768, 3072L * 768, 768L * 3072);
  embed_k<<<6144, tb, 0, stream>>>(x, pos, cls, xb);

  for (int l = 0; l < L_; l++) {
    // QKV: 128^2 2-phase
    gemm_bt<0><<<dim3(64, 18), tb, 0, stream>>>(xb, qkvt + (size_t)l * 2304 * 768,
                                                8192, 2304, 768, bqkv + l * 2304,
                                                nullptr, nullptr, qkvb, vtb, 0);
    // attn: QBLK=128, 8 waves
    attn_k<<<dim3(8, 12, 8), dim3(512), 0, stream>>>(qkvb, vtb, mask, attb);
    // Wo: 128^2 2-phase split-K S=2 (ksl=384, 768 blocks = 3/CU), bf16 partials
    gemm_bt<3><<<dim3(64, 6, 2), tb, 0, stream>>>(attb, wot + (size_t)l * 768 * 768,
                                                  8192, 768, 768, nullptr,
                                                  slA, slB, nullptr, nullptr, 384);
    // ln1: resid = xb (layer input), writes xb (hid)
    ln_red_k<false><<<8192, dim3(192), 0, stream>>>(slA, slB, xb, bo + l * 768,
                                                    ln1g + l * 768, ln1b + l * 768,
                                                    nullptr, xb);
    // FF1: 128^2 2-phase (gelu)
    gemm_bt<2><<<dim3(64, 24), tb, 0, stream>>>(xb, wf1t + (size_t)l * 3072 * 768,
                                                8192, 3072, 768, bf1 + l * 3072,
                                                nullptr, nullptr, ffb, nullptr, 0);
    // FF2: 256^2 8-phase split-K S=2 (ksl=1536), bf16 partials
    gemm256s<<<dim3(32, 3, 2), 512, 131072, stream>>>(ffb, wf2t + (size_t)l * 768 * 3072,
                                                      8192, 768, 3072,
                                                      slA, slB, 1536);
    // ln2: resid = xb (hid), writes xb (out) or final f32 d_out
    if (l < L_ - 1) {
      ln_red_k<false><<<8192, dim3(192), 0, stream>>>(slA, slB, xb, bf2w + l * 768,
                                                      ln2g + l * 768, ln2b + l * 768,
                                                      nullptr, xb);
    } else {
      ln_red_k<true><<<8192, dim3(192), 0, stream>>>(slA, slB, xb, bf2w + l * 768,
                                                     ln2g + l * 768, ln2b + l * 768,
                                                     (float*)d_out, nullptr);
    }
  }
}